// Round 7
// baseline (15119.391 us; speedup 1.0000x reference)
//
#include <hip/hip_runtime.h>

#define B_ 64
#define T_ 4096
#define IN_ 128
#define H_ 256
#define TPB 512

using u64 = unsigned long long;
using u32 = unsigned int;

static constexpr int HB_STRIDE = B_ * H_;                 // u64 per parity buffer
static constexpr size_t HBF_U64 = 2ull * HB_STRIDE;       // fast (L2) buffer, u64
static constexpr size_t HBS_U64 = 2ull * HB_STRIDE;       // slow (agent) buffer, u64
static constexpr size_t CLEAR_BYTES = (HBF_U64 + HBS_U64) * 8 + 2048;

__device__ __forceinline__ float rdlane_f(float v, int k) {
    return __builtin_bit_cast(float, __builtin_amdgcn_readlane(__builtin_bit_cast(int, v), k));
}
__device__ __forceinline__ float fast_rcp(float x) { return __builtin_amdgcn_rcpf(x); }
__device__ __forceinline__ float fast_sigmoid(float x) {
    return fast_rcp(1.0f + __expf(-x));
}
__device__ __forceinline__ float fast_tanh(float x) {
    float ax = fabsf(x);
    float e  = __expf(-2.0f * ax);
    float t  = (1.0f - e) * fast_rcp(1.0f + e);
    return copysignf(t, x);
}
__device__ __forceinline__ u64 ld_agent(const u64* p) {
    return __hip_atomic_load(p, __ATOMIC_RELAXED, __HIP_MEMORY_SCOPE_AGENT);
}
__device__ __forceinline__ void st_agent(u64* p, u64 v) {
    __hip_atomic_store(p, v, __ATOMIC_RELAXED, __HIP_MEMORY_SCOPE_AGENT);
}
// same-XCD L2 exchange primitives: L1 is write-through, L2 is the XCD coherence point
__device__ __forceinline__ u64 ld_sc0(const u64* p) {     // bypass L1, read shared L2
    u64 r;
    asm volatile("global_load_dwordx2 %0, %1, off sc0\n\ts_waitcnt vmcnt(0)"
                 : "=v"(r) : "v"(p) : "memory");
    return r;
}
__device__ __forceinline__ void st_plain(u64* p, u64 v) { // write-through L1 -> own L2
    asm volatile("global_store_dwordx2 %0, %1, off" :: "v"(p), "v"(v) : "memory");
}
// barrier draining LDS only — publish stores stay in flight across it
__device__ __forceinline__ void barrier_lgkm() {
    asm volatile("s_waitcnt lgkmcnt(0)" ::: "memory");
    __builtin_amdgcn_s_barrier();
}

__global__ __launch_bounds__(TPB, 2) void lstm_persist(
    const float* __restrict__ x,      // [B,T,IN]
    const float* __restrict__ W_ih,   // [1024,128]
    const float* __restrict__ W_hh,   // [1024,256]
    const float* __restrict__ b_ih,
    const float* __restrict__ b_hh,
    const float* __restrict__ fc_w,   // [128,256]
    const float* __restrict__ fc_b,   // [128]
    float* __restrict__ out,          // [B,128]
    u64* hbF, u64* hbS, u32* ctrl)
{
    const int tid  = threadIdx.x;
    const int lane = tid & 63;
    const int wave = tid >> 6;

    // ---- runtime XCD-verified work assignment (leader = thread 0) ----
    __shared__ int sh_b, sh_s, sh_fast;
    if (tid == 0) {
        u32 xcd;
        asm volatile("s_getreg_b32 %0, hwreg(HW_REG_XCC_ID)" : "=s"(xcd));
        xcd &= 7;
        u32* tick    = ctrl;            // 8 counters, stride 32 u32
        u32* checkin = ctrl + 256;
        u32* claimed = ctrl + 288;      // 256-bit bitmap
        const u32 slot = __hip_atomic_fetch_add(&tick[xcd * 32], 1u,
                                                __ATOMIC_RELAXED, __HIP_MEMORY_SCOPE_AGENT);
        int b = -1, s = 0, fast = 0;
        if (slot < 32) {
            b = (int)(xcd * 8 + (slot >> 2));
            s = (int)(slot & 3);
            const u32 idx = (u32)(b * 4 + s);
            __hip_atomic_fetch_or(&claimed[idx >> 5], 1u << (idx & 31),
                                  __ATOMIC_RELAXED, __HIP_MEMORY_SCOPE_AGENT);
        }
        __hip_atomic_fetch_add(checkin, 1u, __ATOMIC_RELEASE, __HIP_MEMORY_SCOPE_AGENT);
        while (__hip_atomic_load(checkin, __ATOMIC_ACQUIRE, __HIP_MEMORY_SCOPE_AGENT) < 256u) {}
        if (slot < 32) {
            // FAST iff all 4 slices of this batch were claimed on this XCD
            const u32 nx = __hip_atomic_load(&tick[xcd * 32], __ATOMIC_RELAXED,
                                             __HIP_MEMORY_SCOPE_AGENT);
            const u32 reg = nx < 32u ? nx : 32u;
            fast = ((slot & ~3u) + 4u <= reg) ? 1 : 0;
        } else {
            // overflow: grab any unclaimed (b,s) — cross-XCD, SLOW mode
            int idx = -1;
            while (idx < 0) {
                for (int i = 0; i < 256 && idx < 0; ++i) {
                    const u32 m = 1u << (i & 31);
                    u32 w = __hip_atomic_load(&claimed[i >> 5], __ATOMIC_RELAXED,
                                              __HIP_MEMORY_SCOPE_AGENT);
                    if (!(w & m)) {
                        u32 old = __hip_atomic_fetch_or(&claimed[i >> 5], m,
                                                        __ATOMIC_RELAXED, __HIP_MEMORY_SCOPE_AGENT);
                        if (!(old & m)) idx = i;
                    }
                }
            }
            b = idx >> 2; s = idx & 3; fast = 0;
        }
        sh_b = b; sh_s = s; sh_fast = fast;
    }
    __syncthreads();
    const int  b      = sh_b;
    const int  s      = sh_s;              // h-slice this block PRODUCES
    const bool fastm  = (sh_fast != 0);
    const int  chunk  = wave & 3;          // h-chunk this wave CONSUMES
    const int  sub    = wave >> 2;         // 32-wide K sub-chunk
    const bool is_upd = (wave == s);       // producer wave

    const int row_base = s * 64 + lane;
    const int k_hh = chunk * 64 + sub * 32;
    const int k_ih = chunk * 32 + sub * 16;

    // --- persistent weights: 4 rows x 32 K (hh) + 4 rows x 16 K (ih) ---
    float w_hh[4][32];
    #pragma unroll
    for (int g = 0; g < 4; ++g) {
        const float4* src = (const float4*)(W_hh + (size_t)(g * 256 + row_base) * H_ + k_hh);
        #pragma unroll
        for (int q = 0; q < 8; ++q) {
            const float4 v = src[q];
            w_hh[g][q*4+0] = v.x; w_hh[g][q*4+1] = v.y;
            w_hh[g][q*4+2] = v.z; w_hh[g][q*4+3] = v.w;
        }
    }
    float w_ih[4][16];
    #pragma unroll
    for (int g = 0; g < 4; ++g) {
        const float4* src = (const float4*)(W_ih + (size_t)(g * 256 + row_base) * IN_ + k_ih);
        #pragma unroll
        for (int q = 0; q < 4; ++q) {
            const float4 v = src[q];
            w_ih[g][q*4+0] = v.x; w_ih[g][q*4+1] = v.y;
            w_ih[g][q*4+2] = v.z; w_ih[g][q*4+3] = v.w;
        }
    }
    float bias_[4] = {0.f, 0.f, 0.f, 0.f};
    if (is_upd) {
        #pragma unroll
        for (int g = 0; g < 4; ++g)
            bias_[g] = b_ih[g * 256 + row_base] + b_hh[g * 256 + row_base];
    }

    __shared__ float part[2][8][4][64];   // [parity][wave][gate][h-idx] (R3 layout)

    float h_own = 0.0f, c_own = 0.0f;     // producer wave state

    const float* xb = x + (size_t)b * T_ * IN_;
    float vx  = xb[k_ih + (lane & 15)];             // x(0)
    float vx1 = xb[IN_ + k_ih + (lane & 15)];       // x(1)

    u64* const hstF  = hbF + (size_t)b * H_ + s * 64 + lane;
    u64* const hstS  = hbS + (size_t)b * H_ + s * 64 + lane;
    const u64* const pollF0 = hbF + (size_t)b * H_ + chunk * 64 + lane;
    const u64* const pollS0 = hbS + (size_t)b * H_ + chunk * 64 + lane;

    for (int t = 0; t < T_; ++t) {
        const int p  = t & 1;
        const int pn = p ^ 1;
        float a0 = 0.f, a1 = 0.f, a2 = 0.f, a3 = 0.f;

        const u64* ppF = pollF0 + (size_t)p * HB_STRIDE;
        const u64* ppS = pollS0 + (size_t)p * HB_STRIDE;

        // SLOW mode: early agent probe, RT hides under ih FMAs
        u64 vspec = 0;
        if (!is_upd && !fastm) vspec = ld_agent(ppS);

        // ih contribution — independent of h
        #pragma unroll
        for (int k = 0; k < 16; ++k) {
            const float xv = rdlane_f(vx, k);
            a0 = fmaf(xv, w_ih[0][k], a0);
            a1 = fmaf(xv, w_ih[1][k], a1);
            a2 = fmaf(xv, w_ih[2][k], a2);
            a3 = fmaf(xv, w_ih[3][k], a3);
        }
        vx = vx1;

        // obtain this wave's h-chunk
        float vh;
        if (is_upd) {
            vh = h_own;                            // register fast path
        } else {
            u64 v;
            const unsigned tv = (unsigned)t;
            if (fastm) {
                // XCD-local: sc0 spin against the shared L2 (+agent escape)
                int k = 0;
                for (;;) {
                    v = ld_sc0(ppF);
                    if ((unsigned)(v >> 32) >= tv) break;
                    if ((++k & 15) == 0) {
                        u64 w = ld_agent(ppS);
                        if ((unsigned)(w >> 32) >= tv) { v = w; break; }
                    }
                }
            } else {
                v = vspec;
                if ((unsigned)(v >> 32) < tv) {
                    do { v = ld_agent(ppS); } while ((unsigned)(v >> 32) < tv);
                }
            }
            vh = __builtin_bit_cast(float, (unsigned)v);
        }

        // x prefetch distance 2, issued AFTER spin resolution so the spin's
        // vmcnt(0) never waits on an in-flight HBM x-load
        {
            const int tf = (t + 2 < T_) ? (t + 2) : (T_ - 1);
            vx1 = xb[(size_t)tf * IN_ + k_ih + (lane & 15)];
        }

        // hh FMAs: 1 readlane + 4 fmac per k
        if (sub == 0) {
            #pragma unroll
            for (int k = 0; k < 32; ++k) {
                const float hv = rdlane_f(vh, k);
                a0 = fmaf(hv, w_hh[0][k], a0);
                a1 = fmaf(hv, w_hh[1][k], a1);
                a2 = fmaf(hv, w_hh[2][k], a2);
                a3 = fmaf(hv, w_hh[3][k], a3);
            }
        } else {
            #pragma unroll
            for (int k = 0; k < 32; ++k) {
                const float hv = rdlane_f(vh, 32 + k);
                a0 = fmaf(hv, w_hh[0][k], a0);
                a1 = fmaf(hv, w_hh[1][k], a1);
                a2 = fmaf(hv, w_hh[2][k], a2);
                a3 = fmaf(hv, w_hh[3][k], a3);
            }
        }

        part[p][wave][0][lane] = a0;
        part[p][wave][1][lane] = a1;
        part[p][wave][2][lane] = a2;
        part[p][wave][3][lane] = a3;

        // LDS-only barrier: publish stores drift across it
        barrier_lgkm();

        if (is_upd) {
            float gi = bias_[0], gf = bias_[1], gg = bias_[2], go = bias_[3];
            #pragma unroll
            for (int pc = 0; pc < 8; ++pc) {
                gi += part[p][pc][0][lane];
                gf += part[p][pc][1][lane];
                gg += part[p][pc][2][lane];
                go += part[p][pc][3][lane];
            }
            const float i_ = fast_sigmoid(gi);
            const float f_ = fast_sigmoid(gf);
            const float g_ = fast_tanh(gg);
            const float o_ = fast_sigmoid(go);
            c_own = fmaf(f_, c_own, i_ * g_);
            h_own = o_ * fast_tanh(c_own);
            const u64 pk = ((u64)(unsigned)(t + 1) << 32)
                         | (u64)__builtin_bit_cast(unsigned, h_own);
            st_plain(hstF + (size_t)pn * HB_STRIDE, pk);   // XCD-local L2 (FAST consumers)
            st_agent(hstS + (size_t)pn * HB_STRIDE, pk);   // device-visible mirror
        }
        // part[] is parity-double-buffered; no second barrier needed
    }

    // ---- final FC: out[b, 32s .. 32s+32) ---- (slow mirror, placement-safe)
    const u64* hT = hbS + (size_t)(T_ & 1) * HB_STRIDE + (size_t)b * H_;
    const int c = s * 32 + (tid >> 4);
    const int q = tid & 15;
    float pacc = 0.0f;
    #pragma unroll
    for (int e = 0; e < 16; ++e) {
        u64 v;
        do { v = ld_agent(hT + q * 16 + e); } while ((unsigned)(v >> 32) < (unsigned)T_);
        pacc = fmaf(fc_w[(size_t)c * H_ + q * 16 + e],
                    __builtin_bit_cast(float, (unsigned)v), pacc);
    }
    pacc += __shfl_xor(pacc, 1);
    pacc += __shfl_xor(pacc, 2);
    pacc += __shfl_xor(pacc, 4);
    pacc += __shfl_xor(pacc, 8);
    if (q == 0) out[(size_t)b * 128 + c] = pacc + fc_b[c];
}

extern "C" void kernel_launch(void* const* d_in, const int* in_sizes, int n_in,
                              void* d_out, int out_size, void* d_ws, size_t ws_size,
                              hipStream_t stream) {
    const float* x    = (const float*)d_in[0];
    const float* W_ih = (const float*)d_in[1];
    const float* W_hh = (const float*)d_in[2];
    const float* b_ih = (const float*)d_in[3];
    const float* b_hh = (const float*)d_in[4];
    const float* fc_w = (const float*)d_in[5];
    const float* fc_b = (const float*)d_in[6];
    float* out = (float*)d_out;

    u64* hbF = (u64*)d_ws;
    u64* hbS = hbF + HBF_U64;
    u32* ctrl = (u32*)(hbS + HBS_U64);
    // zero: {ver=0,h=0} initial state + all control counters/bitmaps
    hipMemsetAsync(d_ws, 0, CLEAR_BYTES, stream);

    lstm_persist<<<B_ * 4, TPB, 0, stream>>>(x, W_ih, W_hh, b_ih, b_hh, fc_w, fc_b,
                                             out, hbF, hbS, ctrl);
}

// Round 8
// 6844.149 us; speedup vs baseline: 2.2091x; 2.2091x over previous
//
#include <hip/hip_runtime.h>

#define B_ 64
#define T_ 4096
#define IN_ 128
#define H_ 256
#define TPB 512

using u64 = unsigned long long;
using u32 = unsigned int;

static constexpr int HB_STRIDE = B_ * H_;                 // u64 per parity buffer
static constexpr size_t HBF_U64 = 2ull * HB_STRIDE;       // fast (L2-atomic) buffer
static constexpr size_t HBS_U64 = 2ull * HB_STRIDE;       // slow (agent) buffer
static constexpr size_t CLEAR_BYTES = (HBF_U64 + HBS_U64) * 8 + 2048;

__device__ __forceinline__ float rdlane_f(float v, int k) {
    return __builtin_bit_cast(float, __builtin_amdgcn_readlane(__builtin_bit_cast(int, v), k));
}
__device__ __forceinline__ float fast_rcp(float x) { return __builtin_amdgcn_rcpf(x); }
__device__ __forceinline__ float fast_sigmoid(float x) {
    return fast_rcp(1.0f + __expf(-x));
}
__device__ __forceinline__ float fast_tanh(float x) {
    float ax = fabsf(x);
    float e  = __expf(-2.0f * ax);
    float t  = (1.0f - e) * fast_rcp(1.0f + e);
    return copysignf(t, x);
}
__device__ __forceinline__ u64 ld_agent(const u64* p) {
    return __hip_atomic_load(p, __ATOMIC_RELAXED, __HIP_MEMORY_SCOPE_AGENT);
}
__device__ __forceinline__ void st_agent(u64* p, u64 v) {
    __hip_atomic_store(p, v, __ATOMIC_RELAXED, __HIP_MEMORY_SCOPE_AGENT);
}
// --- same-XCD L2 exchange via ATOMICS (RMW is forced to the L2 copy) ---
__device__ __forceinline__ u64 atomic_probe_l2(const u64* p) {    // add 0, return old
    u64 r, z = 0;
    asm volatile("global_atomic_add_x2 %0, %1, %2, off sc0\n\ts_waitcnt vmcnt(0)"
                 : "=v"(r) : "v"(p), "v"(z) : "memory");
    return r;
}
__device__ __forceinline__ void atomic_pub_l2(u64* p, u64 v) {    // swap, no return
    asm volatile("global_atomic_swap_x2 %0, %1, off" :: "v"(p), "v"(v) : "memory");
}
// barrier draining LDS only — publish stores / x prefetch stay in flight
__device__ __forceinline__ void barrier_lgkm() {
    asm volatile("s_waitcnt lgkmcnt(0)" ::: "memory");
    __builtin_amdgcn_s_barrier();
}

__global__ __launch_bounds__(TPB, 2) void lstm_persist(
    const float* __restrict__ x,      // [B,T,IN]
    const float* __restrict__ W_ih,   // [1024,128]
    const float* __restrict__ W_hh,   // [1024,256]
    const float* __restrict__ b_ih,
    const float* __restrict__ b_hh,
    const float* __restrict__ fc_w,   // [128,256]
    const float* __restrict__ fc_b,   // [128]
    float* __restrict__ out,          // [B,128]
    u64* hbF, u64* hbS, u32* ctrl)
{
    const int tid  = threadIdx.x;
    const int lane = tid & 63;
    const int wave = tid >> 6;

    // ---- runtime XCD-verified work assignment (leader = thread 0) ----
    __shared__ int sh_b, sh_s, sh_fast;
    if (tid == 0) {
        u32 xcd;
        asm volatile("s_getreg_b32 %0, hwreg(HW_REG_XCC_ID)" : "=s"(xcd));
        xcd &= 7;
        u32* tick    = ctrl;            // 8 counters, stride 32 u32
        u32* checkin = ctrl + 256;
        u32* claimed = ctrl + 288;      // 256-bit bitmap
        const u32 slot = __hip_atomic_fetch_add(&tick[xcd * 32], 1u,
                                                __ATOMIC_RELAXED, __HIP_MEMORY_SCOPE_AGENT);
        int b = -1, s = 0, fast = 0;
        if (slot < 32) {
            b = (int)(xcd * 8 + (slot >> 2));
            s = (int)(slot & 3);
            const u32 idx = (u32)(b * 4 + s);
            __hip_atomic_fetch_or(&claimed[idx >> 5], 1u << (idx & 31),
                                  __ATOMIC_RELAXED, __HIP_MEMORY_SCOPE_AGENT);
        }
        __hip_atomic_fetch_add(checkin, 1u, __ATOMIC_RELEASE, __HIP_MEMORY_SCOPE_AGENT);
        while (__hip_atomic_load(checkin, __ATOMIC_ACQUIRE, __HIP_MEMORY_SCOPE_AGENT) < 256u) {}
        if (slot < 32) {
            const u32 nx = __hip_atomic_load(&tick[xcd * 32], __ATOMIC_RELAXED,
                                             __HIP_MEMORY_SCOPE_AGENT);
            const u32 reg = nx < 32u ? nx : 32u;
            fast = ((slot & ~3u) + 4u <= reg) ? 1 : 0;
        } else {
            int idx = -1;
            while (idx < 0) {
                for (int i = 0; i < 256 && idx < 0; ++i) {
                    const u32 mk = 1u << (i & 31);
                    u32 w = __hip_atomic_load(&claimed[i >> 5], __ATOMIC_RELAXED,
                                              __HIP_MEMORY_SCOPE_AGENT);
                    if (!(w & mk)) {
                        u32 old = __hip_atomic_fetch_or(&claimed[i >> 5], mk,
                                                        __ATOMIC_RELAXED, __HIP_MEMORY_SCOPE_AGENT);
                        if (!(old & mk)) idx = i;
                    }
                }
            }
            b = idx >> 2; s = idx & 3; fast = 0;
        }
        sh_b = b; sh_s = s; sh_fast = fast;
    }
    __syncthreads();
    const int  b      = sh_b;
    const int  s      = sh_s;              // h-slice this block PRODUCES
    const bool fastm  = (sh_fast != 0);
    const int  chunk  = wave & 3;          // h-chunk this wave CONSUMES
    const int  sub    = wave >> 2;         // 32-wide K sub-chunk
    const bool is_upd = (wave == s);       // producer wave

    const int row_base = s * 64 + lane;
    const int k_hh = chunk * 64 + sub * 32;
    const int k_ih = chunk * 32 + sub * 16;

    // --- persistent weights: 4 rows x 32 K (hh) + 4 rows x 16 K (ih) ---
    float w_hh[4][32];
    #pragma unroll
    for (int g = 0; g < 4; ++g) {
        const float4* src = (const float4*)(W_hh + (size_t)(g * 256 + row_base) * H_ + k_hh);
        #pragma unroll
        for (int q = 0; q < 8; ++q) {
            const float4 v = src[q];
            w_hh[g][q*4+0] = v.x; w_hh[g][q*4+1] = v.y;
            w_hh[g][q*4+2] = v.z; w_hh[g][q*4+3] = v.w;
        }
    }
    float w_ih[4][16];
    #pragma unroll
    for (int g = 0; g < 4; ++g) {
        const float4* src = (const float4*)(W_ih + (size_t)(g * 256 + row_base) * IN_ + k_ih);
        #pragma unroll
        for (int q = 0; q < 4; ++q) {
            const float4 v = src[q];
            w_ih[g][q*4+0] = v.x; w_ih[g][q*4+1] = v.y;
            w_ih[g][q*4+2] = v.z; w_ih[g][q*4+3] = v.w;
        }
    }
    float bias_[4] = {0.f, 0.f, 0.f, 0.f};
    if (is_upd) {
        #pragma unroll
        for (int g = 0; g < 4; ++g)
            bias_[g] = b_ih[g * 256 + row_base] + b_hh[g * 256 + row_base];
    }

    __shared__ float part[2][8][4][64];   // [parity][wave][gate][h-idx] (R3 layout)

    float h_own = 0.0f, c_own = 0.0f;     // producer wave state

    const float* xb = x + (size_t)b * T_ * IN_;
    float vx  = xb[k_ih + (lane & 15)];             // x(0)
    float vx1 = xb[IN_ + k_ih + (lane & 15)];       // x(1)

    u64* const hstF  = hbF + (size_t)b * H_ + s * 64 + lane;
    u64* const hstS  = hbS + (size_t)b * H_ + s * 64 + lane;
    const u64* const pollF0 = hbF + (size_t)b * H_ + chunk * 64 + lane;
    const u64* const pollS0 = hbS + (size_t)b * H_ + chunk * 64 + lane;

    for (int t = 0; t < T_; ++t) {
        const int p  = t & 1;
        const int pn = p ^ 1;
        float a0 = 0.f, a1 = 0.f, a2 = 0.f, a3 = 0.f;

        const u64* ppF = pollF0 + (size_t)p * HB_STRIDE;
        const u64* ppS = pollS0 + (size_t)p * HB_STRIDE;

        // early agent probe — RT hides under the ih FMAs
        u64 vspec = 0;
        if (!is_upd) vspec = ld_agent(ppS);

        // ih contribution — independent of h
        #pragma unroll
        for (int k = 0; k < 16; ++k) {
            const float xv = rdlane_f(vx, k);
            a0 = fmaf(xv, w_ih[0][k], a0);
            a1 = fmaf(xv, w_ih[1][k], a1);
            a2 = fmaf(xv, w_ih[2][k], a2);
            a3 = fmaf(xv, w_ih[3][k], a3);
        }
        vx = vx1;

        // obtain this wave's h-chunk
        float vh;
        if (is_upd) {
            vh = h_own;                            // register fast path
        } else {
            u64 v = vspec;
            const unsigned tv = (unsigned)t;
            if ((unsigned)(v >> 32) < tv) {
                if (fastm) {
                    // XCD-local: atomic RMW probes read the L2's authoritative copy
                    int k = 0;
                    for (;;) {
                        v = atomic_probe_l2(ppF);
                        if ((unsigned)(v >> 32) >= tv) break;
                        if ((++k & 3) == 0) {
                            u64 w = ld_agent(ppS);
                            if ((unsigned)(w >> 32) >= tv) { v = w; break; }
                        }
                    }
                } else {
                    do { v = ld_agent(ppS); } while ((unsigned)(v >> 32) < tv);
                }
            }
            vh = __builtin_bit_cast(float, (unsigned)v);
        }

        // x prefetch distance 2, AFTER spin resolution (never on the spin's vmcnt)
        {
            const int tf = (t + 2 < T_) ? (t + 2) : (T_ - 1);
            vx1 = xb[(size_t)tf * IN_ + k_ih + (lane & 15)];
        }

        // hh FMAs: 1 readlane + 4 fmac per k
        if (sub == 0) {
            #pragma unroll
            for (int k = 0; k < 32; ++k) {
                const float hv = rdlane_f(vh, k);
                a0 = fmaf(hv, w_hh[0][k], a0);
                a1 = fmaf(hv, w_hh[1][k], a1);
                a2 = fmaf(hv, w_hh[2][k], a2);
                a3 = fmaf(hv, w_hh[3][k], a3);
            }
        } else {
            #pragma unroll
            for (int k = 0; k < 32; ++k) {
                const float hv = rdlane_f(vh, 32 + k);
                a0 = fmaf(hv, w_hh[0][k], a0);
                a1 = fmaf(hv, w_hh[1][k], a1);
                a2 = fmaf(hv, w_hh[2][k], a2);
                a3 = fmaf(hv, w_hh[3][k], a3);
            }
        }

        part[p][wave][0][lane] = a0;
        part[p][wave][1][lane] = a1;
        part[p][wave][2][lane] = a2;
        part[p][wave][3][lane] = a3;

        // LDS-only barrier: in-flight global ops ride across
        barrier_lgkm();

        if (is_upd) {
            float gi = bias_[0], gf = bias_[1], gg = bias_[2], go = bias_[3];
            #pragma unroll
            for (int pc = 0; pc < 8; ++pc) {
                gi += part[p][pc][0][lane];
                gf += part[p][pc][1][lane];
                gg += part[p][pc][2][lane];
                go += part[p][pc][3][lane];
            }
            const float i_ = fast_sigmoid(gi);
            const float f_ = fast_sigmoid(gf);
            const float g_ = fast_tanh(gg);
            const float o_ = fast_sigmoid(go);
            c_own = fmaf(f_, c_own, i_ * g_);
            h_own = o_ * fast_tanh(c_own);
            const u64 pk = ((u64)(unsigned)(t + 1) << 32)
                         | (u64)__builtin_bit_cast(unsigned, h_own);
            atomic_pub_l2(hstF + (size_t)pn * HB_STRIDE, pk);  // L2-visible publish
            st_agent(hstS + (size_t)pn * HB_STRIDE, pk);       // device-visible mirror
        }
        // part[] is parity-double-buffered; no second barrier needed
    }

    // ---- final FC: out[b, 32s .. 32s+32) ---- (slow mirror, placement-safe)
    const u64* hT = hbS + (size_t)(T_ & 1) * HB_STRIDE + (size_t)b * H_;
    const int c = s * 32 + (tid >> 4);
    const int q = tid & 15;
    float pacc = 0.0f;
    #pragma unroll
    for (int e = 0; e < 16; ++e) {
        u64 v;
        do { v = ld_agent(hT + q * 16 + e); } while ((unsigned)(v >> 32) < (unsigned)T_);
        pacc = fmaf(fc_w[(size_t)c * H_ + q * 16 + e],
                    __builtin_bit_cast(float, (unsigned)v), pacc);
    }
    pacc += __shfl_xor(pacc, 1);
    pacc += __shfl_xor(pacc, 2);
    pacc += __shfl_xor(pacc, 4);
    pacc += __shfl_xor(pacc, 8);
    if (q == 0) out[(size_t)b * 128 + c] = pacc + fc_b[c];
}

extern "C" void kernel_launch(void* const* d_in, const int* in_sizes, int n_in,
                              void* d_out, int out_size, void* d_ws, size_t ws_size,
                              hipStream_t stream) {
    const float* x    = (const float*)d_in[0];
    const float* W_ih = (const float*)d_in[1];
    const float* W_hh = (const float*)d_in[2];
    const float* b_ih = (const float*)d_in[3];
    const float* b_hh = (const float*)d_in[4];
    const float* fc_w = (const float*)d_in[5];
    const float* fc_b = (const float*)d_in[6];
    float* out = (float*)d_out;

    u64* hbF = (u64*)d_ws;
    u64* hbS = hbF + HBF_U64;
    u32* ctrl = (u32*)(hbS + HBS_U64);
    // zero: {ver=0,h=0} initial state + all control counters/bitmaps
    hipMemsetAsync(d_ws, 0, CLEAR_BYTES, stream);

    lstm_persist<<<B_ * 4, TPB, 0, stream>>>(x, W_ih, W_hh, b_ih, b_hh, fc_w, fc_b,
                                             out, hbF, hbS, ctrl);
}